// Round 1
// baseline (17618.695 us; speedup 1.0000x reference)
//
#include <hip/hip_runtime.h>
#include <hip/hip_bf16.h>
#include <hip/hip_cooperative_groups.h>

namespace cg = cooperative_groups;

#define E   512
#define H   1024
#define BB  32
#define TT  512
#define G4  4096            // 4*H
// d_out layout: ys [32][512][1024] fp32, then hn [32][1024], then cn [32][1024]
#define YS_ELEMS 16777216

typedef __attribute__((ext_vector_type(8))) short bf16x8;   // 8 bf16 in 4 VGPRs
typedef __attribute__((ext_vector_type(4))) float f32x4;

__device__ __forceinline__ unsigned short f2bf(float x){
    union { float f; unsigned u; } v; v.f = x;
    unsigned r = v.u + 0x7fffu + ((v.u >> 16) & 1u);   // RNE
    return (unsigned short)(r >> 16);
}
__device__ __forceinline__ float bf2f(unsigned short b){
    union { unsigned u; float f; } v; v.u = ((unsigned)b) << 16;
    return v.f;
}
__device__ __forceinline__ float sigm(float x){ return 1.f/(1.f+__expf(-x)); }
__device__ __forceinline__ float tanh_(float x){ return 2.f/(1.f+__expf(-2.f*x)) - 1.f; }

// ---------------- prep: gather+cast A, cast W_ih/W_hh/h0 to bf16 ----------------
// grid = 7184 blocks x 256 thr; each thread converts 8 consecutive floats.
__global__ void k_prep(const int* __restrict__ ids, const float* __restrict__ emb,
                       const float* __restrict__ Wih, const float* __restrict__ Whh,
                       const float* __restrict__ h0,
                       unsigned short* __restrict__ Abf, unsigned short* __restrict__ Bbf,
                       unsigned short* __restrict__ Wb,  unsigned short* __restrict__ hb)
{
    int bx = blockIdx.x, tx = threadIdx.x;
    const float* src; unsigned short* dst;
    if (bx < 4096) {                       // A gather: m = t*32+b, row = ids[b][t]
        unsigned u = bx*256u + tx;
        int m  = u >> 6;                   // 0..16383
        int e0 = (u & 63) * 8;             // 0..504
        int row = ids[(m & 31) * TT + (m >> 5)];
        src = emb + (size_t)row * E + e0;
        dst = Abf + (size_t)m   * E + e0;
    } else if (bx < 5120) {                // W_ih: 2,097,152 elems
        size_t off = ((size_t)(bx-4096)*256u + tx) * 8;
        src = Wih + off; dst = Bbf + off;
    } else if (bx < 7168) {                // W_hh: 4,194,304 elems
        size_t off = ((size_t)(bx-5120)*256u + tx) * 8;
        src = Whh + off; dst = Wb + off;
    } else {                               // h0: 32,768 elems
        size_t off = ((size_t)(bx-7168)*256u + tx) * 8;
        src = h0 + off; dst = hb + off;
    }
    float4 f0 = *(const float4*)(src);
    float4 f1 = *(const float4*)(src + 4);
    uint4 o;
    o.x = f2bf(f0.x) | ((unsigned)f2bf(f0.y) << 16);
    o.y = f2bf(f0.z) | ((unsigned)f2bf(f0.w) << 16);
    o.z = f2bf(f1.x) | ((unsigned)f2bf(f1.y) << 16);
    o.w = f2bf(f1.z) | ((unsigned)f2bf(f1.w) << 16);
    *(uint4*)dst = o;
}

// ---------------- x_proj GEMM: C[m][n] = sum_k A[m][k]*W_ih[n][k], bf16 out ------
// 128x128 tile, 256 thr = 4 waves (2x2), each wave 4x4 MFMA tiles of 16x16x32.
__global__ __launch_bounds__(256) void k_gemm(const unsigned short* __restrict__ A,
        const unsigned short* __restrict__ Bm, unsigned short* __restrict__ C)
{
    __shared__ __align__(16) unsigned short As[128][40];   // +8 pad: 2-way banks (free)
    __shared__ __align__(16) unsigned short Bs[128][40];
    int tid = threadIdx.x;
    int bm = blockIdx.x & 127;             // 128 m-tiles
    int bn = blockIdx.x >> 7;              // 32 n-tiles
    int w = tid >> 6, lane = tid & 63, l15 = lane & 15, quad = lane >> 4;
    int wm = w & 1, wn = w >> 1;
    f32x4 acc[4][4] = {};
    for (int kt = 0; kt < 16; ++kt) {
        __syncthreads();
        for (int i = 0; i < 2; ++i) {      // stage 128x32 of A and B
            int c = tid + 256*i;
            int row = c >> 2, kc = (c & 3) * 8;
            *(uint4*)&As[row][kc] = *(const uint4*)(A  + ((size_t)(bm*128 + row))*E + kt*32 + kc);
            *(uint4*)&Bs[row][kc] = *(const uint4*)(Bm + ((size_t)(bn*128 + row))*E + kt*32 + kc);
        }
        __syncthreads();
        bf16x8 af[4], bfr[4];
        for (int i = 0; i < 4; ++i) af[i]  = *(const bf16x8*)&As[wm*64 + i*16 + l15][quad*8];
        for (int j = 0; j < 4; ++j) bfr[j] = *(const bf16x8*)&Bs[wn*64 + j*16 + l15][quad*8];
        for (int i = 0; i < 4; ++i)
            for (int j = 0; j < 4; ++j)
                acc[i][j] = __builtin_amdgcn_mfma_f32_16x16x32_bf16(af[i], bfr[j], acc[i][j], 0,0,0);
    }
    // C/D layout: col = lane&15 (n), row = quad*4+reg (m)
    for (int i = 0; i < 4; ++i)
        for (int j = 0; j < 4; ++j)
            for (int r = 0; r < 4; ++r) {
                int mg = bm*128 + wm*64 + i*16 + quad*4 + r;
                int ng = bn*128 + wn*64 + j*16 + l15;
                C[(size_t)mg * G4 + ng] = f2bf(acc[i][j][r]);
            }
}

// ---------------- recurrence: cooperative, 256 blocks x 256 thr ------------------
// Block blk owns h-indices kg = blk*4 .. blk*4+3 (16 W_hh rows, LDS-resident).
// Per step: gates[32 x 16] = h[32 x 1024] @ Ws^T via MFMA (K split over 2 wave
// pairs, M split 2), LDS-reduce, 128 epilogue threads update c (registers) and h.
__global__ __launch_bounds__(256) void k_recur(const unsigned short* __restrict__ xp,
        const unsigned short* __restrict__ Wb, unsigned short* __restrict__ hbuf,
        const float* __restrict__ c0, float* __restrict__ out)
{
    __shared__ __align__(16) unsigned short Ws[16][1032];  // +8 pad -> 2-way banks
    __shared__ float gbuf[2][32][16];                      // [khalf][b][n]
    cg::grid_group grid = cg::this_grid();
    int tid = threadIdx.x;
    int blk = blockIdx.x;
    int w = tid >> 6, lane = tid & 63, l15 = lane & 15, quad = lane >> 4;
    int kh = w >> 1, m0 = (w & 1) * 16;

    // Load this block's 16 W_hh rows (q*1024 + blk*4 + kl), as Ws[n= q*4+kl][k]
    for (int c = 0; c < 8; ++c) {
        int id = tid + 256*c;              // 0..2047
        int n = id >> 7, kc = (id & 127) * 8;
        int grow = (n >> 2) * H + blk*4 + (n & 3);
        *(uint4*)&Ws[n][kc] = *(const uint4*)(Wb + (size_t)grow * H + kc);
    }
    int b  = tid & 31, kl = tid >> 5;      // epilogue mapping (valid tid<128)
    int kg = blk*4 + kl;
    float c_st = 0.f;
    if (tid < 128) c_st = c0[b*H + kg];
    __syncthreads();

    for (int t = 0; t < TT; ++t) {
        const unsigned short* cur = hbuf + (t & 1) * (BB*H);
        unsigned short*       nxt = hbuf + ((t+1) & 1) * (BB*H);
        float xf[4] = {0.f,0.f,0.f,0.f};
        if (tid < 128) {                   // prefetch x_proj[t] early (hides HBM lat)
            for (int q = 0; q < 4; ++q)
                xf[q] = bf2f(xp[((size_t)t*BB + b)*G4 + q*H + kg]);
        }
        f32x4 acc = {};
        for (int k2 = 0; k2 < 16; ++k2) {
            int kt = kh*16 + k2;
            bf16x8 a  = *(const bf16x8*)(cur + (size_t)(m0 + l15)*H + kt*32 + quad*8);
            bf16x8 bf = *(const bf16x8*)&Ws[l15][kt*32 + quad*8];
            acc = __builtin_amdgcn_mfma_f32_16x16x32_bf16(a, bf, acc, 0,0,0);
        }
        for (int r = 0; r < 4; ++r)
            gbuf[kh][m0 + quad*4 + r][l15] = acc[r];
        __syncthreads();
        if (tid < 128) {
            float pre[4];
            for (int q = 0; q < 4; ++q)
                pre[q] = gbuf[0][b][q*4 + kl] + gbuf[1][b][q*4 + kl] + xf[q];
            float ci = sigm(pre[0]), cf = sigm(pre[1]);
            float gg = tanh_(pre[2]), co = sigm(pre[3]);
            c_st = cf * c_st + ci * gg;
            float h = co * tanh_(c_st);
            out[(size_t)b * (TT*H) + (size_t)t * H + kg] = h;   // ys fp32
            nxt[b*H + kg] = f2bf(h);                            // bf16 state
            if (t == TT-1) {
                out[YS_ELEMS + b*H + kg]         = h;           // hn
                out[YS_ELEMS + 32768 + b*H + kg] = c_st;        // cn
            }
        }
        grid.sync();   // h(t+1) visible to all blocks; also covers gbuf reuse
    }
}

// ---------------- launch --------------------------------------------------------
extern "C" void kernel_launch(void* const* d_in, const int* in_sizes, int n_in,
                              void* d_out, int out_size, void* d_ws, size_t ws_size,
                              hipStream_t stream)
{
    const int*   ids = (const int*)  d_in[0];
    const float* h0  = (const float*)d_in[1];
    const float* c0  = (const float*)d_in[2];
    const float* emb = (const float*)d_in[3];
    const float* Wih = (const float*)d_in[4];
    const float* Whh = (const float*)d_in[5];
    float* out = (float*)d_out;
    char* ws = (char*)d_ws;
    // ws layout (needs ~156.1 MiB):
    unsigned short* xp  = (unsigned short*)(ws);                          // 134,217,728 B
    unsigned short* Abf = (unsigned short*)(ws + 134217728);              //  16,777,216 B
    unsigned short* Bbf = (unsigned short*)(ws + 134217728 + 16777216);   //   4,194,304 B
    unsigned short* Wb  = (unsigned short*)(ws + 134217728 + 16777216 + 4194304);          // 8,388,608 B
    unsigned short* hb  = (unsigned short*)(ws + 134217728 + 16777216 + 4194304 + 8388608); //  131,072 B

    k_prep<<<7184, 256, 0, stream>>>(ids, emb, Wih, Whh, h0, Abf, Bbf, Wb, hb);
    k_gemm<<<4096, 256, 0, stream>>>(Abf, Bbf, xp);
    void* args[] = { (void*)&xp, (void*)&Wb, (void*)&hb, (void*)&c0, (void*)&out };
    hipLaunchCooperativeKernel((void*)k_recur, dim3(256), dim3(256), args, 0, stream);
}

// Round 2
// 4647.142 us; speedup vs baseline: 3.7913x; 3.7913x over previous
//
#include <hip/hip_runtime.h>
#include <hip/hip_bf16.h>
#include <hip/hip_cooperative_groups.h>

#define E   512
#define H   1024
#define BB  32
#define TT  512
#define G4  4096            // 4*H
// d_out layout: ys [32][512][1024] fp32, then hn [32][1024], then cn [32][1024]
#define YS_ELEMS 16777216

typedef __attribute__((ext_vector_type(8))) short bf16x8;   // 8 bf16 in 4 VGPRs
typedef __attribute__((ext_vector_type(4))) float f32x4;

// Barrier counter for the recurrence (device global: survives graph capture,
// re-zeroed by k_prep every launch so replays are self-contained).
__device__ unsigned g_cnt;

__device__ __forceinline__ unsigned short f2bf(float x){
    union { float f; unsigned u; } v; v.f = x;
    unsigned r = v.u + 0x7fffu + ((v.u >> 16) & 1u);   // RNE
    return (unsigned short)(r >> 16);
}
__device__ __forceinline__ float bf2f(unsigned short b){
    union { unsigned u; float f; } v; v.u = ((unsigned)b) << 16;
    return v.f;
}
__device__ __forceinline__ float sigm(float x){ return 1.f/(1.f+__expf(-x)); }
__device__ __forceinline__ float tanh_(float x){ return 2.f/(1.f+__expf(-2.f*x)) - 1.f; }

// ---------------- prep: gather+cast A, cast W_ih/W_hh/h0 to bf16 ----------------
__global__ void k_prep(const int* __restrict__ ids, const float* __restrict__ emb,
                       const float* __restrict__ Wih, const float* __restrict__ Whh,
                       const float* __restrict__ h0,
                       unsigned short* __restrict__ Abf, unsigned short* __restrict__ Bbf,
                       unsigned short* __restrict__ Wb,  unsigned short* __restrict__ hb)
{
    int bx = blockIdx.x, tx = threadIdx.x;
    if (bx == 0 && tx == 0)   // reset recurrence barrier (agent-visible)
        __hip_atomic_store(&g_cnt, 0u, __ATOMIC_RELAXED, __HIP_MEMORY_SCOPE_AGENT);
    const float* src; unsigned short* dst;
    if (bx < 4096) {                       // A gather: m = t*32+b, row = ids[b][t]
        unsigned u = bx*256u + tx;
        int m  = u >> 6;                   // 0..16383
        int e0 = (u & 63) * 8;             // 0..504
        int row = ids[(m & 31) * TT + (m >> 5)];
        src = emb + (size_t)row * E + e0;
        dst = Abf + (size_t)m   * E + e0;
    } else if (bx < 5120) {                // W_ih: 2,097,152 elems
        size_t off = ((size_t)(bx-4096)*256u + tx) * 8;
        src = Wih + off; dst = Bbf + off;
    } else if (bx < 7168) {                // W_hh: 4,194,304 elems
        size_t off = ((size_t)(bx-5120)*256u + tx) * 8;
        src = Whh + off; dst = Wb + off;
    } else {                               // h0: 32,768 elems
        size_t off = ((size_t)(bx-7168)*256u + tx) * 8;
        src = h0 + off; dst = hb + off;
    }
    float4 f0 = *(const float4*)(src);
    float4 f1 = *(const float4*)(src + 4);
    uint4 o;
    o.x = f2bf(f0.x) | ((unsigned)f2bf(f0.y) << 16);
    o.y = f2bf(f0.z) | ((unsigned)f2bf(f0.w) << 16);
    o.z = f2bf(f1.x) | ((unsigned)f2bf(f1.y) << 16);
    o.w = f2bf(f1.z) | ((unsigned)f2bf(f1.w) << 16);
    *(uint4*)dst = o;
}

// ---------------- x_proj GEMM: C[m][n] = sum_k A[m][k]*W_ih[n][k], bf16 out ------
__global__ __launch_bounds__(256) void k_gemm(const unsigned short* __restrict__ A,
        const unsigned short* __restrict__ Bm, unsigned short* __restrict__ C)
{
    __shared__ __align__(16) unsigned short As[128][40];
    __shared__ __align__(16) unsigned short Bs[128][40];
    int tid = threadIdx.x;
    int bm = blockIdx.x & 127;
    int bn = blockIdx.x >> 7;
    int w = tid >> 6, lane = tid & 63, l15 = lane & 15, quad = lane >> 4;
    int wm = w & 1, wn = w >> 1;
    f32x4 acc[4][4] = {};
    for (int kt = 0; kt < 16; ++kt) {
        __syncthreads();
        for (int i = 0; i < 2; ++i) {
            int c = tid + 256*i;
            int row = c >> 2, kc = (c & 3) * 8;
            *(uint4*)&As[row][kc] = *(const uint4*)(A  + ((size_t)(bm*128 + row))*E + kt*32 + kc);
            *(uint4*)&Bs[row][kc] = *(const uint4*)(Bm + ((size_t)(bn*128 + row))*E + kt*32 + kc);
        }
        __syncthreads();
        bf16x8 af[4], bfr[4];
        for (int i = 0; i < 4; ++i) af[i]  = *(const bf16x8*)&As[wm*64 + i*16 + l15][quad*8];
        for (int j = 0; j < 4; ++j) bfr[j] = *(const bf16x8*)&Bs[wn*64 + j*16 + l15][quad*8];
        for (int i = 0; i < 4; ++i)
            for (int j = 0; j < 4; ++j)
                acc[i][j] = __builtin_amdgcn_mfma_f32_16x16x32_bf16(af[i], bfr[j], acc[i][j], 0,0,0);
    }
    for (int i = 0; i < 4; ++i)
        for (int j = 0; j < 4; ++j)
            for (int r = 0; r < 4; ++r) {
                int mg = bm*128 + wm*64 + i*16 + quad*4 + r;
                int ng = bn*128 + wn*64 + j*16 + l15;
                C[(size_t)mg * G4 + ng] = f2bf(acc[i][j][r]);
            }
}

// ---------------- recurrence: 256 blocks x 256 thr, hand-rolled LLC barrier ------
// Block blk owns h-indices kg = blk*4..blk*4+3 (16 W_hh rows LDS-resident).
// Cross-block data (h, barrier counter) moves ONLY via agent-scope relaxed
// atomics (sc0/sc1: bypass non-coherent L1/L2, coherent at Infinity Cache).
// Ordering: wave 0 holds ALL h-stores; inline s_waitcnt vmcnt(0) drains them
// before tid0's arrival atomicAdd, so pollers observing cnt>=256*t see h(t).
__global__ __launch_bounds__(256) void k_recur(const unsigned short* __restrict__ xp,
        const unsigned short* __restrict__ Wb, unsigned short* __restrict__ hbuf,
        const float* __restrict__ c0, float* __restrict__ out)
{
    __shared__ __align__(16) unsigned short Ws[16][1032];  // +8 pad
    __shared__ float gbuf[2][32][16];                      // [khalf][b][n]
    int tid = threadIdx.x;
    int blk = blockIdx.x;
    int w = tid >> 6, lane = tid & 63, l15 = lane & 15, quad = lane >> 4;
    int kh = w >> 1, m0 = (w & 1) * 16;

    // Load this block's 16 W_hh rows as Ws[n = q*4+kl][k]
    for (int c = 0; c < 8; ++c) {
        int id = tid + 256*c;
        int n = id >> 7, kc = (id & 127) * 8;
        int grow = (n >> 2) * H + blk*4 + (n & 3);
        *(uint4*)&Ws[n][kc] = *(const uint4*)(Wb + (size_t)grow * H + kc);
    }
    // epilogue mapping: tid<64 (wave 0), each thread owns 2 adjacent h-columns
    int b  = tid & 31;
    int kp = (tid >> 5) & 1;
    int kg0 = blk*4 + kp*2;                // even -> 4B/8B aligned pair stores
    float cA = 0.f, cB = 0.f;
    if (tid < 64) {
        float2 cc = *(const float2*)(c0 + b*H + kg0);
        cA = cc.x; cB = cc.y;
    }
    __syncthreads();

    for (int t = 0; t < TT; ++t) {
        const unsigned short* cur = hbuf + (t & 1) * (BB*H);
        unsigned short*       nxt = hbuf + ((t+1) & 1) * (BB*H);
        // prefetch x_proj[t] (plain loads, read-only data) before the barrier wait
        float xA[4], xB[4];
        if (tid < 64) {
            #pragma unroll
            for (int q = 0; q < 4; ++q) {
                unsigned x2 = *(const unsigned*)(xp + ((size_t)t*BB + b)*G4 + q*H + kg0);
                xA[q] = bf2f((unsigned short)(x2 & 0xffffu));
                xB[q] = bf2f((unsigned short)(x2 >> 16));
            }
        }
        // ---- barrier: wait for all 256 productions of h(t) ----
        if (tid == 0) {
            while (__hip_atomic_load(&g_cnt, __ATOMIC_RELAXED, __HIP_MEMORY_SCOPE_AGENT)
                   < 256u * (unsigned)t) { }
        }
        __syncthreads();
        // ---- gates = h(t) @ Ws^T (K split over wave pairs, M split x2) ----
        f32x4 acc = {};
        #pragma unroll
        for (int k2 = 0; k2 < 16; ++k2) {
            int kt = kh*16 + k2;
            const unsigned long long* pa =
                (const unsigned long long*)(cur + (size_t)(m0 + l15)*H + kt*32 + quad*8);
            union { unsigned long long q[2]; bf16x8 v; } ua;
            ua.q[0] = __hip_atomic_load(pa,     __ATOMIC_RELAXED, __HIP_MEMORY_SCOPE_AGENT);
            ua.q[1] = __hip_atomic_load(pa + 1, __ATOMIC_RELAXED, __HIP_MEMORY_SCOPE_AGENT);
            bf16x8 bfr = *(const bf16x8*)&Ws[l15][kt*32 + quad*8];
            acc = __builtin_amdgcn_mfma_f32_16x16x32_bf16(ua.v, bfr, acc, 0,0,0);
        }
        #pragma unroll
        for (int r = 0; r < 4; ++r)
            gbuf[kh][m0 + quad*4 + r][l15] = acc[r];
        __syncthreads();
        // ---- epilogue: 64 threads x (2 columns each) ----
        if (tid < 64) {
            float pA[4], pB[4];
            #pragma unroll
            for (int q = 0; q < 4; ++q) {
                int ca = q*4 + kp*2;
                pA[q] = gbuf[0][b][ca]   + gbuf[1][b][ca]   + xA[q];
                pB[q] = gbuf[0][b][ca+1] + gbuf[1][b][ca+1] + xB[q];
            }
            float iA = sigm(pA[0]), fA = sigm(pA[1]), gA = tanh_(pA[2]), oA = sigm(pA[3]);
            float iB = sigm(pB[0]), fB = sigm(pB[1]), gB = tanh_(pB[2]), oB = sigm(pB[3]);
            cA = fA * cA + iA * gA;
            cB = fB * cB + iB * gB;
            float hA = oA * tanh_(cA);
            float hB = oB * tanh_(cB);
            *(float2*)(out + (size_t)b*(TT*H) + (size_t)t*H + kg0) = make_float2(hA, hB);
            unsigned hp = (unsigned)f2bf(hA) | ((unsigned)f2bf(hB) << 16);
            __hip_atomic_store((unsigned*)(nxt + b*H + kg0), hp,
                               __ATOMIC_RELAXED, __HIP_MEMORY_SCOPE_AGENT);
            if (t == TT-1) {
                *(float2*)(out + YS_ELEMS + b*H + kg0)         = make_float2(hA, hB);
                *(float2*)(out + YS_ELEMS + 32768 + b*H + kg0) = make_float2(cA, cB);
            }
        }
        // drain wave-0's h stores to the coherence point, then arrive
        asm volatile("s_waitcnt vmcnt(0)" ::: "memory");
        if (tid == 0)
            __hip_atomic_fetch_add(&g_cnt, 1u, __ATOMIC_RELAXED, __HIP_MEMORY_SCOPE_AGENT);
    }
}

// ---------------- launch --------------------------------------------------------
extern "C" void kernel_launch(void* const* d_in, const int* in_sizes, int n_in,
                              void* d_out, int out_size, void* d_ws, size_t ws_size,
                              hipStream_t stream)
{
    const int*   ids = (const int*)  d_in[0];
    const float* h0  = (const float*)d_in[1];
    const float* c0  = (const float*)d_in[2];
    const float* emb = (const float*)d_in[3];
    const float* Wih = (const float*)d_in[4];
    const float* Whh = (const float*)d_in[5];
    float* out = (float*)d_out;
    char* ws = (char*)d_ws;
    unsigned short* xp  = (unsigned short*)(ws);                          // 134,217,728 B
    unsigned short* Abf = (unsigned short*)(ws + 134217728);              //  16,777,216 B
    unsigned short* Bbf = (unsigned short*)(ws + 134217728 + 16777216);   //   4,194,304 B
    unsigned short* Wb  = (unsigned short*)(ws + 134217728 + 16777216 + 4194304);          // 8,388,608 B
    unsigned short* hb  = (unsigned short*)(ws + 134217728 + 16777216 + 4194304 + 8388608); //  131,072 B

    k_prep<<<7184, 256, 0, stream>>>(ids, emb, Wih, Whh, h0, Abf, Bbf, Wb, hb);
    k_gemm<<<4096, 256, 0, stream>>>(Abf, Bbf, xp);
    void* args[] = { (void*)&xp, (void*)&Wb, (void*)&hb, (void*)&c0, (void*)&out };
    hipLaunchCooperativeKernel((void*)k_recur, dim3(256), dim3(256), args, 0, stream);
}

// Round 4
// 3547.575 us; speedup vs baseline: 4.9664x; 1.3099x over previous
//
#include <hip/hip_runtime.h>
#include <hip/hip_bf16.h>
#include <hip/hip_cooperative_groups.h>

#define E   512
#define H   1024
#define BB  32
#define TT  512
#define G4  4096            // 4*H
// d_out layout: ys [32][512][1024] fp32, then hn [32][1024], then cn [32][1024]
#define YS_ELEMS 16777216

typedef __attribute__((ext_vector_type(8))) short bf16x8;   // 8 bf16 in 4 VGPRs
typedef __attribute__((ext_vector_type(4))) float f32x4;

__device__ __forceinline__ unsigned short f2bf(float x){
    union { float f; unsigned u; } v; v.f = x;
    unsigned r = v.u + 0x7fffu + ((v.u >> 16) & 1u);   // RNE
    return (unsigned short)(r >> 16);
}
__device__ __forceinline__ float bf2f(unsigned short b){
    union { unsigned u; float f; } v; v.u = ((unsigned)b) << 16;
    return v.f;
}
__device__ __forceinline__ float sigm(float x){ return 1.f/(1.f+__expf(-x)); }
__device__ __forceinline__ float tanh_(float x){ return 2.f/(1.f+__expf(-2.f*x)) - 1.f; }

// ---------------- prep: gather+cast A, cast W_ih/W_hh/h0 to bf16; zero flags ----
__global__ void k_prep(const int* __restrict__ ids, const float* __restrict__ emb,
                       const float* __restrict__ Wih, const float* __restrict__ Whh,
                       const float* __restrict__ h0,
                       unsigned short* __restrict__ Abf, unsigned short* __restrict__ Bbf,
                       unsigned short* __restrict__ Wb,  unsigned short* __restrict__ hb,
                       unsigned* __restrict__ flags)
{
    int bx = blockIdx.x, tx = threadIdx.x;
    if (bx == 0) flags[tx] = 0;            // ws is poisoned 0xAA every launch
    const float* src; unsigned short* dst;
    if (bx < 4096) {                       // A gather: m = t*32+b, row = ids[b][t]
        unsigned u = bx*256u + tx;
        int m  = u >> 6;                   // 0..16383
        int e0 = (u & 63) * 8;             // 0..504
        int row = ids[(m & 31) * TT + (m >> 5)];
        src = emb + (size_t)row * E + e0;
        dst = Abf + (size_t)m   * E + e0;
    } else if (bx < 5120) {                // W_ih: 2,097,152 elems
        size_t off = ((size_t)(bx-4096)*256u + tx) * 8;
        src = Wih + off; dst = Bbf + off;
    } else if (bx < 7168) {                // W_hh: 4,194,304 elems
        size_t off = ((size_t)(bx-5120)*256u + tx) * 8;
        src = Whh + off; dst = Wb + off;
    } else {                               // h0: 32,768 elems
        size_t off = ((size_t)(bx-7168)*256u + tx) * 8;
        src = h0 + off; dst = hb + off;
    }
    float4 f0 = *(const float4*)(src);
    float4 f1 = *(const float4*)(src + 4);
    uint4 o;
    o.x = f2bf(f0.x) | ((unsigned)f2bf(f0.y) << 16);
    o.y = f2bf(f0.z) | ((unsigned)f2bf(f0.w) << 16);
    o.z = f2bf(f1.x) | ((unsigned)f2bf(f1.y) << 16);
    o.w = f2bf(f1.z) | ((unsigned)f2bf(f1.w) << 16);
    *(uint4*)dst = o;
}

// ---------------- x_proj GEMM: C[m][n] = sum_k A[m][k]*W_ih[n][k], bf16 out ------
__global__ __launch_bounds__(256) void k_gemm(const unsigned short* __restrict__ A,
        const unsigned short* __restrict__ Bm, unsigned short* __restrict__ C)
{
    __shared__ __align__(16) unsigned short As[128][40];
    __shared__ __align__(16) unsigned short Bs[128][40];
    int tid = threadIdx.x;
    int bm = blockIdx.x & 127;
    int bn = blockIdx.x >> 7;
    int w = tid >> 6, lane = tid & 63, l15 = lane & 15, quad = lane >> 4;
    int wm = w & 1, wn = w >> 1;
    f32x4 acc[4][4] = {};
    for (int kt = 0; kt < 16; ++kt) {
        __syncthreads();
        for (int i = 0; i < 2; ++i) {
            int c = tid + 256*i;
            int row = c >> 2, kc = (c & 3) * 8;
            *(uint4*)&As[row][kc] = *(const uint4*)(A  + ((size_t)(bm*128 + row))*E + kt*32 + kc);
            *(uint4*)&Bs[row][kc] = *(const uint4*)(Bm + ((size_t)(bn*128 + row))*E + kt*32 + kc);
        }
        __syncthreads();
        bf16x8 af[4], bfr[4];
        for (int i = 0; i < 4; ++i) af[i]  = *(const bf16x8*)&As[wm*64 + i*16 + l15][quad*8];
        for (int j = 0; j < 4; ++j) bfr[j] = *(const bf16x8*)&Bs[wn*64 + j*16 + l15][quad*8];
        for (int i = 0; i < 4; ++i)
            for (int j = 0; j < 4; ++j)
                acc[i][j] = __builtin_amdgcn_mfma_f32_16x16x32_bf16(af[i], bfr[j], acc[i][j], 0,0,0);
    }
    for (int i = 0; i < 4; ++i)
        for (int j = 0; j < 4; ++j)
            for (int r = 0; r < 4; ++r) {
                int mg = bm*128 + wm*64 + i*16 + quad*4 + r;
                int ng = bn*128 + wn*64 + j*16 + l15;
                C[(size_t)mg * G4 + ng] = f2bf(acc[i][j][r]);
            }
}

// ---------------- recurrence: 256 blocks x 256 thr, distributed-flag barrier -----
// Block blk owns h-indices kg = blk*4..blk*4+3 (16 W_hh rows LDS-resident).
// Cross-block sync: per-block flag (own dword; 16 flags/cacheline -> no RMW
// serialization). Producer drains its h agent-stores (wave 0 holds ALL of them)
// with s_waitcnt vmcnt(0), then agent-stores flags[blk]=t+1. Consumer wave 0:
// 64 lanes x 4 relaxed agent loads cover all 256 flags; spin on __all().
__global__ __launch_bounds__(256) void k_recur(const unsigned short* __restrict__ xp,
        const unsigned short* __restrict__ Wb, unsigned short* __restrict__ hbuf,
        const float* __restrict__ c0, float* __restrict__ out,
        unsigned* __restrict__ flags)
{
    __shared__ __align__(16) unsigned short Ws[16][1032];  // +8 pad
    __shared__ float gbuf[2][32][17];                      // [khalf][b][n], +1 pad
    int tid = threadIdx.x;
    int blk = blockIdx.x;
    int w = tid >> 6, lane = tid & 63, l15 = lane & 15, quad = lane >> 4;
    int kh = w >> 1, m0 = (w & 1) * 16;

    // Load this block's 16 W_hh rows as Ws[n = q*4+kl][k]
    for (int c = 0; c < 8; ++c) {
        int id = tid + 256*c;
        int n = id >> 7, kc = (id & 127) * 8;
        int grow = (n >> 2) * H + blk*4 + (n & 3);
        *(uint4*)&Ws[n][kc] = *(const uint4*)(Wb + (size_t)grow * H + kc);
    }
    // epilogue mapping: tid<64 (wave 0), each thread owns 2 adjacent h-columns
    int b  = tid & 31;
    int kp = (tid >> 5) & 1;
    int kg0 = blk*4 + kp*2;
    float cA = 0.f, cB = 0.f;
    if (tid < 64) {
        float2 cc = *(const float2*)(c0 + b*H + kg0);
        cA = cc.x; cB = cc.y;
    }
    __syncthreads();

    for (int t = 0; t < TT; ++t) {
        const unsigned short* cur = hbuf + (t & 1) * (BB*H);
        unsigned short*       nxt = hbuf + ((t+1) & 1) * (BB*H);
        // prefetch x_proj[t] (read-only) before the barrier wait
        float xA[4], xB[4];
        if (tid < 64) {
            #pragma unroll
            for (int q = 0; q < 4; ++q) {
                unsigned x2 = *(const unsigned*)(xp + ((size_t)t*BB + b)*G4 + q*H + kg0);
                xA[q] = bf2f((unsigned short)(x2 & 0xffffu));
                xB[q] = bf2f((unsigned short)(x2 >> 16));
            }
        }
        // ---- barrier: wait until every block has published h(t) ----
        if (tid < 64) {
            unsigned tgt = (unsigned)t;
            const unsigned* fp = flags + lane*4;
            bool ok;
            do {
                unsigned f0 = __hip_atomic_load(fp+0, __ATOMIC_RELAXED, __HIP_MEMORY_SCOPE_AGENT);
                unsigned f1 = __hip_atomic_load(fp+1, __ATOMIC_RELAXED, __HIP_MEMORY_SCOPE_AGENT);
                unsigned f2 = __hip_atomic_load(fp+2, __ATOMIC_RELAXED, __HIP_MEMORY_SCOPE_AGENT);
                unsigned f3 = __hip_atomic_load(fp+3, __ATOMIC_RELAXED, __HIP_MEMORY_SCOPE_AGENT);
                ok = (f0 >= tgt) & (f1 >= tgt) & (f2 >= tgt) & (f3 >= tgt);
            } while (!__all(ok));
        }
        __syncthreads();
        // ---- gates = h(t) @ Ws^T (K split over wave pairs, M split x2) ----
        f32x4 acc = {};
        #pragma unroll
        for (int k2 = 0; k2 < 16; ++k2) {
            int kt = kh*16 + k2;
            const unsigned long long* pa =
                (const unsigned long long*)(cur + (size_t)(m0 + l15)*H + kt*32 + quad*8);
            union { unsigned long long q[2]; bf16x8 v; } ua;
            ua.q[0] = __hip_atomic_load(pa,     __ATOMIC_RELAXED, __HIP_MEMORY_SCOPE_AGENT);
            ua.q[1] = __hip_atomic_load(pa + 1, __ATOMIC_RELAXED, __HIP_MEMORY_SCOPE_AGENT);
            bf16x8 bfr = *(const bf16x8*)&Ws[l15][kt*32 + quad*8];
            acc = __builtin_amdgcn_mfma_f32_16x16x32_bf16(ua.v, bfr, acc, 0,0,0);
        }
        #pragma unroll
        for (int r = 0; r < 4; ++r)
            gbuf[kh][m0 + quad*4 + r][l15] = acc[r];
        __syncthreads();
        // ---- epilogue: 64 threads x (2 columns each) ----
        if (tid < 64) {
            float pA[4], pB[4];
            #pragma unroll
            for (int q = 0; q < 4; ++q) {
                int ca = q*4 + kp*2;
                pA[q] = gbuf[0][b][ca]   + gbuf[1][b][ca]   + xA[q];
                pB[q] = gbuf[0][b][ca+1] + gbuf[1][b][ca+1] + xB[q];
            }
            float iA = sigm(pA[0]), fA = sigm(pA[1]), gA = tanh_(pA[2]), oA = sigm(pA[3]);
            float iB = sigm(pB[0]), fB = sigm(pB[1]), gB = tanh_(pB[2]), oB = sigm(pB[3]);
            cA = fA * cA + iA * gA;
            cB = fB * cB + iB * gB;
            float hA = oA * tanh_(cA);
            float hB = oB * tanh_(cB);
            // 1) publish h(t+1) to the coherence point
            unsigned hp = (unsigned)f2bf(hA) | ((unsigned)f2bf(hB) << 16);
            __hip_atomic_store((unsigned*)(nxt + b*H + kg0), hp,
                               __ATOMIC_RELAXED, __HIP_MEMORY_SCOPE_AGENT);
            // 2) drain wave-0's vmem (h stores included), then raise our flag
            asm volatile("s_waitcnt vmcnt(0)" ::: "memory");
            if (tid == 0)
                __hip_atomic_store(&flags[blk], (unsigned)(t+1),
                                   __ATOMIC_RELAXED, __HIP_MEMORY_SCOPE_AGENT);
            // 3) off-critical-path output stores
            *(float2*)(out + (size_t)b*(TT*H) + (size_t)t*H + kg0) = make_float2(hA, hB);
            if (t == TT-1) {
                *(float2*)(out + YS_ELEMS + b*H + kg0)         = make_float2(hA, hB);
                *(float2*)(out + YS_ELEMS + 32768 + b*H + kg0) = make_float2(cA, cB);
            }
        }
    }
}

// ---------------- launch --------------------------------------------------------
extern "C" void kernel_launch(void* const* d_in, const int* in_sizes, int n_in,
                              void* d_out, int out_size, void* d_ws, size_t ws_size,
                              hipStream_t stream)
{
    const int*   ids = (const int*)  d_in[0];
    const float* h0  = (const float*)d_in[1];
    const float* c0  = (const float*)d_in[2];
    const float* emb = (const float*)d_in[3];
    const float* Wih = (const float*)d_in[4];
    const float* Whh = (const float*)d_in[5];
    float* out = (float*)d_out;
    char* ws = (char*)d_ws;
    unsigned short* xp  = (unsigned short*)(ws);                          // 134,217,728 B
    unsigned short* Abf = (unsigned short*)(ws + 134217728);              //  16,777,216 B
    unsigned short* Bbf = (unsigned short*)(ws + 134217728 + 16777216);   //   4,194,304 B
    unsigned short* Wb  = (unsigned short*)(ws + 134217728 + 16777216 + 4194304);          // 8,388,608 B
    unsigned short* hb  = (unsigned short*)(ws + 134217728 + 16777216 + 4194304 + 8388608); //  131,072 B
    unsigned*       fl  = (unsigned*)      (ws + 134217728 + 16777216 + 4194304 + 8388608 + 131072); // 1,024 B

    k_prep<<<7184, 256, 0, stream>>>(ids, emb, Wih, Whh, h0, Abf, Bbf, Wb, hb, fl);
    k_gemm<<<4096, 256, 0, stream>>>(Abf, Bbf, xp);
    void* args[] = { (void*)&xp, (void*)&Wb, (void*)&hb, (void*)&c0, (void*)&out, (void*)&fl };
    hipLaunchCooperativeKernel((void*)k_recur, dim3(256), dim3(256), args, 0, stream);
}